// Round 6
// baseline (885.553 us; speedup 1.0000x reference)
//
#include <hip/hip_runtime.h>
#include <math.h>
#include <float.h>

// EMAVectorQuantizer eval path.
//   z: [8, 64, 64, 64] fp32  (B, C=d=64, H, W);  weight: [4096, 64] fp32
//   N = 32768 rows, K = 4096 codes.
//
// d_out (flat fp32): z_q[2097152] | loss | perplexity | encodings[32768*4096] | indices[32768]
#define ZQ_OFF   0
#define LOSS_OFF 2097152
#define PERP_OFF 2097153
#define ENC_OFF  2097154
#define IDX_OFF  136314882ULL
#define BETA     0.25f

#define WSTRIDE  36   // b128-conflict-free: 8 consecutive lanes tile all 32 banks

// ws layout: [0..4) loss fp32 acc | [4..8) ticket int | [16..16+16384) hist int[4096]
//            [16400 .. +16384) wnorm fp32[4096]

__global__ void vq_wnorm(const float* __restrict__ w, float* __restrict__ wnorm) {
    int c = blockIdx.x * 256 + threadIdx.x;
    const float4* w4 = (const float4*)(w + ((size_t)c << 6));
    float s = 0.f;
    #pragma unroll
    for (int k = 0; k < 16; ++k) { float4 v = w4[k]; s += v.x*v.x + v.y*v.y + v.z*v.z + v.w*v.w; }
    wnorm[c] = s;
}

// 4 rows (I0..I0+3, components of ZV) x 4 codes, one d step
#define FMA4x4(ZV, I0, W0, W1, W2, W3) \
    acc[(I0)  ][0]=fmaf((ZV).x,(W0),acc[(I0)  ][0]); acc[(I0)  ][1]=fmaf((ZV).x,(W1),acc[(I0)  ][1]); \
    acc[(I0)  ][2]=fmaf((ZV).x,(W2),acc[(I0)  ][2]); acc[(I0)  ][3]=fmaf((ZV).x,(W3),acc[(I0)  ][3]); \
    acc[(I0)+1][0]=fmaf((ZV).y,(W0),acc[(I0)+1][0]); acc[(I0)+1][1]=fmaf((ZV).y,(W1),acc[(I0)+1][1]); \
    acc[(I0)+1][2]=fmaf((ZV).y,(W2),acc[(I0)+1][2]); acc[(I0)+1][3]=fmaf((ZV).y,(W3),acc[(I0)+1][3]); \
    acc[(I0)+2][0]=fmaf((ZV).z,(W0),acc[(I0)+2][0]); acc[(I0)+2][1]=fmaf((ZV).z,(W1),acc[(I0)+2][1]); \
    acc[(I0)+2][2]=fmaf((ZV).z,(W2),acc[(I0)+2][2]); acc[(I0)+2][3]=fmaf((ZV).z,(W3),acc[(I0)+2][3]); \
    acc[(I0)+3][0]=fmaf((ZV).w,(W0),acc[(I0)+3][0]); acc[(I0)+3][1]=fmaf((ZV).w,(W1),acc[(I0)+3][1]); \
    acc[(I0)+3][2]=fmaf((ZV).w,(W2),acc[(I0)+3][2]); acc[(I0)+3][3]=fmaf((ZV).w,(W3),acc[(I0)+3][3]);

// one d (= d0+e): 16 rows x 4 codes
#define STEP_E(E, WC0, WC1, WC2, WC3) { \
    float4 za = *(const float4*)&zD[d0 + (E)][trow * 16];      \
    float4 zb = *(const float4*)&zD[d0 + (E)][trow * 16 + 4];  \
    float4 zc = *(const float4*)&zD[d0 + (E)][trow * 16 + 8];  \
    float4 zd = *(const float4*)&zD[d0 + (E)][trow * 16 + 12]; \
    FMA4x4(za, 0,  WC0, WC1, WC2, WC3)  \
    FMA4x4(zb, 4,  WC0, WC1, WC2, WC3)  \
    FMA4x4(zc, 8,  WC0, WC1, WC2, WC3)  \
    FMA4x4(zd, 12, WC0, WC1, WC2, WC3)  \
}

// Block: 256 threads = 4 rowgroups (trow=tx>>6, one per wave) x 64 colgroups (tcol).
// Thread tile: 16 rows x 4 codes (codes = cbase + tcol + 64k). Chunk = 256 codes,
// d in 2 x 32 slices (32 phases). Register-double-buffered w staging.
// Zero-fill of encodings is done by a prior hipMemsetAsync, NOT in this kernel.
__global__ __launch_bounds__(256, 2) void vq_main(
    const float* __restrict__ z, const float* __restrict__ w,
    const float* __restrict__ wnorm, float* __restrict__ out,
    float* __restrict__ loss_ws, int* __restrict__ ticket, int* __restrict__ hist)
{
    __shared__ float zD[64][64];         // [d][row-in-block], 16 KB
    __shared__ float wl[256 * WSTRIDE];  // [c_local][32-d slice], 36.9 KB
    __shared__ int   s_widx[64];
    __shared__ int   s_flag;

    const int tx   = threadIdx.x;
    const int tcol = tx & 63;            // colgroup: codes cbase + tcol + 64k
    const int trow = tx >> 6;            // rowgroup: rows trow*16 .. +16 (wave-uniform)
    const int base = blockIdx.x * 64;    // global rows [base, base+64)
    const int bb   = base >> 12;         // b
    const int hh   = (base & 4095) >> 6; // h   (w coordinate = row-in-block)

    // ---- stage zD[d][wcol] = z[bb][d][hh][wcol] ----
    #pragma unroll
    for (int j = 0; j < 4; ++j) {
        int f4 = j * 256 + tx;
        int d  = f4 >> 4, w4i = f4 & 15;
        float4 v = *(const float4*)(z + (((size_t)bb * 64 + d) * 64 + hh) * 64 + w4i * 4);
        *(float4*)&zD[d][w4i * 4] = v;
    }

    float best[16]; int bidx[16];
    #pragma unroll
    for (int i = 0; i < 16; ++i) { best[i] = FLT_MAX; bidx[i] = 0; }

    float* enc = out + ENC_OFF;

    // staging geometry: thread writes c_local = j*32 + stc, quad stq of the 32-d slice
    const int stc = tx >> 3;             // 0..31
    const int stq = tx & 7;              // 0..7
    float4 pw[8];
    #pragma unroll
    for (int j = 0; j < 8; ++j)
        pw[j] = ((const float4*)w)[(size_t)(j * 32 + stc) * 16 + stq];   // chunk 0, slice 0

    float acc[16][4];
    float wn[4];

    for (int p = 0; p < 32; ++p) {
        const int ch = p >> 1, s = p & 1;
        const int cbase = ch << 8;

        __syncthreads();                 // previous-phase wl readers done
        #pragma unroll
        for (int j = 0; j < 8; ++j)
            *(float4*)&wl[(j * 32 + stc) * WSTRIDE + stq * 4] = pw[j];
        __syncthreads();                 // wl ready

        // prefetch NEXT phase's w slice (lands during this phase's compute)
        {
            const int pn = (p < 31) ? p + 1 : 31;
            const int cbn = (pn >> 1) << 8, sn = pn & 1;
            #pragma unroll
            for (int j = 0; j < 8; ++j)
                pw[j] = ((const float4*)w)[(size_t)(cbn + j * 32 + stc) * 16 + sn * 8 + stq];
        }

        if (s == 0) {
            #pragma unroll
            for (int k = 0; k < 4; ++k) wn[k] = wnorm[cbase + tcol + 64 * k];
            #pragma unroll
            for (int i = 0; i < 16; ++i)
                #pragma unroll
                for (int k = 0; k < 4; ++k) acc[i][k] = 0.f;
        }

        // compute this 32-d slice: 8 groups of 4 d's
        #pragma unroll
        for (int dg = 0; dg < 8; ++dg) {
            const int d0 = s * 32 + dg * 4;
            float4 wv0 = *(const float4*)&wl[(tcol      ) * WSTRIDE + dg * 4];
            float4 wv1 = *(const float4*)&wl[(tcol +  64) * WSTRIDE + dg * 4];
            float4 wv2 = *(const float4*)&wl[(tcol + 128) * WSTRIDE + dg * 4];
            float4 wv3 = *(const float4*)&wl[(tcol + 192) * WSTRIDE + dg * 4];
            STEP_E(0, wv0.x, wv1.x, wv2.x, wv3.x)
            STEP_E(1, wv0.y, wv1.y, wv2.y, wv3.y)
            STEP_E(2, wv0.z, wv1.z, wv2.z, wv3.z)
            STEP_E(3, wv0.w, wv1.w, wv2.w, wv3.w)
        }

        if (s == 1) {
            // fold into running argmin (codes ascending per thread: k then chunk order)
            #pragma unroll
            for (int i = 0; i < 16; ++i) {
                #pragma unroll
                for (int k = 0; k < 4; ++k) {
                    float scv = fmaf(-2.f, acc[i][k], wn[k]);
                    if (scv < best[i]) { best[i] = scv; bidx[i] = cbase + tcol + 64 * k; }
                }
            }
        }
    }

    // ---- cross-thread argmin reduce (reuse wl as [64][64] float2, 32 KB) ----
    __syncthreads();
    float2* red = (float2*)wl;
    #pragma unroll
    for (int i = 0; i < 16; ++i)
        red[(trow * 16 + i) * 64 + tcol] = make_float2(best[i], __int_as_float(bidx[i]));
    __syncthreads();

    if (tx < 64) {
        float b = FLT_MAX; int bi = 0x7fffffff;
        for (int c = 0; c < 64; ++c) {
            float2 v = red[tx * 64 + c];
            int vi = __float_as_int(v.y);
            if (v.x < b || (v.x == b && vi < bi)) { b = v.x; bi = vi; }
        }
        s_widx[tx] = bi;
        out[IDX_OFF + (size_t)(base + tx)] = (float)bi;
        atomicAdd(&hist[bi], 1);
        enc[((size_t)(base + tx) << 12) + bi] = 1.0f;   // enc pre-zeroed by memset
    }
    __syncthreads();

    // ---- z_q (STE rounding) + commitment loss partial ----
    {
        const int row = tx & 63;
        const int dg  = tx >> 6;           // 4 waves x 16 d each
        const int wi  = s_widx[row];
        const float* qrow = w + ((size_t)wi << 6);
        float lsum = 0.f;
        #pragma unroll
        for (int dd = 0; dd < 16; ++dd) {
            int d = dg * 16 + dd;
            float q  = qrow[d];
            float zv = zD[d][row];
            float diff = q - zv;
            lsum += diff * diff;
            out[ZQ_OFF + (((size_t)bb * 64 + d) * 64 + hh) * 64 + row] = zv + (q - zv);
        }
        #pragma unroll
        for (int off = 32; off > 0; off >>= 1) lsum += __shfl_down(lsum, off, 64);
        if ((tx & 63) == 0) atomicAdd(loss_ws, lsum);
    }

    // ---- fused finalize: last block computes loss scalar + perplexity ----
    __syncthreads();
    if (tx == 0) {
        __threadfence();
        int old = atomicAdd(ticket, 1);
        s_flag = (old == 511) ? 1 : 0;
    }
    __syncthreads();
    if (s_flag) {
        __threadfence();
        float s = 0.f;
        #pragma unroll
        for (int j = 0; j < 16; ++j) {
            int c = tx + j * 256;
            int cnt = atomicAdd(&hist[c], 0);          // device-coherent read
            float p = (float)cnt * (1.f / 32768.f);
            s += p * logf(p + 1e-10f);
        }
        float* fr = wl;
        fr[tx] = s;
        __syncthreads();
        for (int off = 128; off > 0; off >>= 1) {
            if (tx < off) fr[tx] += fr[tx + off];
            __syncthreads();
        }
        if (tx == 0) {
            out[LOSS_OFF] = BETA * atomicAdd(loss_ws, 0.f) / 2097152.f;
            out[PERP_OFF] = expf(-fr[0]);
        }
    }
}

extern "C" void kernel_launch(void* const* d_in, const int* in_sizes, int n_in,
                              void* d_out, int out_size, void* d_ws, size_t ws_size,
                              hipStream_t stream)
{
    const float* z = (const float*)d_in[0];
    const float* w = (const float*)d_in[1];
    float* out     = (float*)d_out;
    float* loss_ws = (float*)d_ws;
    int*   ticket  = (int*)((char*)d_ws + 4);
    int*   hist    = (int*)((char*)d_ws + 16);
    float* wnorm   = (float*)((char*)d_ws + 16400);

    hipMemsetAsync(d_ws, 0, 16 + 4096 * sizeof(int), stream);
    // zero the 512 MB encodings region at full fill bandwidth (clean full-line writes)
    hipMemsetAsync((char*)d_out + (size_t)ENC_OFF * 4, 0,
                   (size_t)32768 * 4096 * 4, stream);
    vq_wnorm<<<16, 256, 0, stream>>>(w, wnorm);
    vq_main<<<512, 256, 0, stream>>>(z, w, wnorm, out, loss_ws, ticket, hist);
}